// Round 14
// baseline (217.320 us; speedup 1.0000x reference)
//
#include <hip/hip_runtime.h>
#include <cmath>

// Problem constants
#define B_TOTAL 262144
#define D 16
#define TE 3
#define H 64

#define TPB 16                       // b-tiles (of 16 rows) per wave
#define NBX (B_TOTAL / 16 / TPB)     // 1024 blocks in x
#define NBY 4                        // d-groups of 4 (4 waves/block, one d each)

#define LOG2E 1.44269504088896340736f
#define LN2   0.693147180559945309417f

// f16 transpose buffer row stride (f16 elems). 72 = 64+8 pad.
#define RSH 72
// A-frag staging stride in dwords (conflict-free ds_read_b64).
#define ARS 10

typedef _Float16 half8  __attribute__((ext_vector_type(8)));
typedef _Float16 half4  __attribute__((ext_vector_type(4)));
typedef __fp16   fp16x2 __attribute__((ext_vector_type(2)));
typedef float    f32x4  __attribute__((ext_vector_type(4)));
typedef unsigned int uint32;

// exp+log softplus (R12: poly regressed — trans issue is cheap, VALU is not).
__device__ __forceinline__ float sp_log2(float xs) {
    return __builtin_amdgcn_logf(1.0f + __builtin_amdgcn_exp2f(xs));
}
__device__ __forceinline__ float softplus_full(float x) {
    float e = __builtin_amdgcn_exp2f(-fabsf(x) * LOG2E);
    return fmaxf(x, 0.0f) + LN2 * __builtin_amdgcn_logf(1.0f + e);
}

// R14: occupancy is pinned at 4 waves/SIMD in every configuration
// (R9/R10/R12/R13), so stall-hiding must come from ILP *within* the wave:
// two tiles are processed per loop iteration, fully interleaved, each with
// its own LDS transpose slice (no false dependency). launch_bounds(256,4):
// cap 128 regs — the doubled transient set (~110 peak) must fit WITHOUT
// spilling (spill signature = FETCH/WRITE balloon; R7/R11 lesson).
__global__ __launch_bounds__(256, 4) void DiagonalVariance_kernel(
    const float* __restrict__ t,   // [B, TE]
    const float* __restrict__ y,   // [B, D]
    const float* __restrict__ W1,  // [D, 4, 64]
    const float* __restrict__ b1,  // [D, 64]
    const float* __restrict__ W2,  // [D, 64, 64]
    const float* __restrict__ b2,  // [D, 64]
    const float* __restrict__ W3,  // [D, 64, 1]
    const float* __restrict__ b3,  // [D, 1]
    float* __restrict__ out)       // [B, D]
{
    __shared__ __align__(16) _Float16 tbuf[4 * 2 * 16 * RSH];  // 18.4 KB: 2 slices/wave
    __shared__ __align__(16) float obuf[TPB * 16 * 4];         // 4 KB
    __shared__ __align__(16) uint32 abuf[256 * ARS];           // 10 KB

    const int wave = threadIdx.x >> 6;
    const int lane = threadIdx.x & 63;
    const int q    = lane >> 4;
    const int lm   = lane & 15;
    const int d    = blockIdx.y * 4 + wave;
    const bool q0  = (q == 0);

    // ---- cooperative input staging: thread i pre-packs row i's A-frag ----
    {
        const int i    = threadIdx.x;
        const int grow = blockIdx.x * 256 + i;
        const f32x4 yv = *(const f32x4*)(y + grow * D + blockIdx.y * 4);
        const float* tpp = t + grow * TE;
        const float tt0 = tpp[0], tt1 = tpp[1], tt2 = tpp[2];
        const uint32 u1 = __builtin_bit_cast(uint32, __builtin_amdgcn_cvt_pkrtz(tt1, tt2));
        uint32* ab = abuf + i * ARS;
        ab[0] = __builtin_bit_cast(uint32, __builtin_amdgcn_cvt_pkrtz(yv.x, tt0)); ab[1] = u1;
        ab[2] = __builtin_bit_cast(uint32, __builtin_amdgcn_cvt_pkrtz(yv.y, tt0)); ab[3] = u1;
        ab[4] = __builtin_bit_cast(uint32, __builtin_amdgcn_cvt_pkrtz(yv.z, tt0)); ab[5] = u1;
        ab[6] = __builtin_bit_cast(uint32, __builtin_amdgcn_cvt_pkrtz(yv.w, tt0)); ab[7] = u1;
    }

    const float* __restrict__ W1d = W1 + d * (4 * H);
    const float* __restrict__ b1d = b1 + d * H;
    const float* __restrict__ W2d = W2 + d * (H * H);
    const float* __restrict__ b2d = b2 + d * H;
    const float* __restrict__ W3d = W3 + d * H;

    // ---------------- one-time per-wave fragment setup ----------------
    half8 w2f[2][4];
    #pragma unroll
    for (int ks = 0; ks < 2; ++ks)
        #pragma unroll
        for (int nt = 0; nt < 4; ++nt)
            #pragma unroll
            for (int j = 0; j < 8; ++j)
                w2f[ks][nt][j] = (_Float16)W2d[(32 * ks + 8 * q + j) * H + 16 * nt + lm];

    half4 w1f[4];
    #pragma unroll
    for (int nt = 0; nt < 4; ++nt) {
        #pragma unroll
        for (int i = 0; i < 4; ++i) {
            const int h = 16 * nt + lm;
            float v = 0.0f;
            if (q == 0)           v = W1d[i * H + h] * LOG2E;
            if (q == 1 && i == 0) v = b1d[h] * LOG2E;
            w1f[nt][i] = (_Float16)v;
        }
    }

    float b2s[4], w3n[4];
    #pragma unroll
    for (int nt = 0; nt < 4; ++nt) {
        b2s[nt] = b2d[16 * nt + lm] * LOG2E;
        w3n[nt] = W3d[16 * nt + lm] * LN2;
    }
    const float b3v = b3[d];

    // two transpose slices per wave (parity u)
    _Float16* twr[2];
    const _Float16* trd[2];
    #pragma unroll
    for (int u = 0; u < 2; ++u) {
        _Float16* const tb = tbuf + (wave * 2 + u) * (16 * RSH);
        twr[u] = tb + (q * 4) * RSH + lm;
        trd[u] = tb + lm * RSH + 8 * q;
    }

    const uint32* const ard = abuf + lm * ARS + 2 * wave;

    __syncthreads();   // staging visible to all waves

    #pragma unroll 1
    for (int tg = 0; tg < TPB; tg += 2) {
        // ---- A-frags for both tiles (independent ds_read_b64s) ----
        f32x4 acc1[2][4];
        #pragma unroll
        for (int u = 0; u < 2; ++u) {
            const uint32 a0 = ard[(tg + u) * 16 * ARS + 0];
            const uint32 a1 = ard[(tg + u) * 16 * ARS + 1];
            union { half4 h; uint32 uu[2]; } af;
            af.uu[0] = q0 ? a0 : 0x00003C00u;
            af.uu[1] = q0 ? a1 : 0u;
            #pragma unroll
            for (int nt = 0; nt < 4; ++nt)
                acc1[u][nt] = __builtin_amdgcn_mfma_f32_16x16x16f16(
                    af.h, w1f[nt], (f32x4){0.f, 0.f, 0.f, 0.f}, 0, 0, 0);
        }

        // ---- softplus + transpose writes, both tiles ----
        #pragma unroll
        for (int u = 0; u < 2; ++u)
            #pragma unroll
            for (int nt = 0; nt < 4; ++nt)
                #pragma unroll
                for (int r = 0; r < 4; ++r)
                    twr[u][r * RSH + nt * 16] = (_Float16)sp_log2(acc1[u][nt][r]);

        // ---- A-frag reads for L2, both tiles ----
        half8 a2[2][2];
        #pragma unroll
        for (int u = 0; u < 2; ++u)
            #pragma unroll
            for (int ks = 0; ks < 2; ++ks)
                a2[u][ks] = *(const half8*)(trd[u] + 32 * ks);

        // ---- L2 MFMAs, interleaved across tiles ----
        f32x4 acc2[2][4];
        #pragma unroll
        for (int u = 0; u < 2; ++u)
            #pragma unroll
            for (int nt = 0; nt < 4; ++nt)
                acc2[u][nt] = __builtin_amdgcn_mfma_f32_16x16x32_f16(
                    a2[u][0], w2f[0][nt], (f32x4){0.f, 0.f, 0.f, 0.f}, 0, 0, 0);
        #pragma unroll
        for (int u = 0; u < 2; ++u)
            #pragma unroll
            for (int nt = 0; nt < 4; ++nt)
                acc2[u][nt] = __builtin_amdgcn_mfma_f32_16x16x32_f16(
                    a2[u][1], w2f[1][nt], acc2[u][nt], 0, 0, 0);

        // ---- L3 dot in C-layout + butterfly, both tiles ----
        float s[2][4];
        #pragma unroll
        for (int u = 0; u < 2; ++u) {
            s[u][0] = s[u][1] = s[u][2] = s[u][3] = 0.f;
            #pragma unroll
            for (int nt = 0; nt < 4; ++nt)
                #pragma unroll
                for (int r = 0; r < 4; ++r)
                    s[u][r] = fmaf(sp_log2(acc2[u][nt][r] + b2s[nt]), w3n[nt], s[u][r]);
        }
        #pragma unroll
        for (int mask = 1; mask < 16; mask <<= 1)
            #pragma unroll
            for (int u = 0; u < 2; ++u)
                #pragma unroll
                for (int r = 0; r < 4; ++r)
                    s[u][r] += __shfl_xor(s[u][r], mask, 64);

        #pragma unroll
        for (int u = 0; u < 2; ++u) {
            const float v01 = (lm & 1) ? s[u][1] : s[u][0];
            const float v23 = (lm & 1) ? s[u][3] : s[u][2];
            const float vs  = (lm & 2) ? v23 : v01;
            if (lm < 4)
                obuf[((tg + u) * 16 + q * 4 + lm) * 4 + wave] = softplus_full(vs + b3v);
        }
    }

    // Single barrier, then f32x4 flush: thread i handles row i (256 rows).
    __syncthreads();
    const int i = threadIdx.x;
    const f32x4 v = *(const f32x4*)(obuf + 4 * i);
    *(f32x4*)(out + (blockIdx.x * 256 + i) * D + blockIdx.y * 4) = v;
}

extern "C" void kernel_launch(void* const* d_in, const int* in_sizes, int n_in,
                              void* d_out, int out_size, void* d_ws, size_t ws_size,
                              hipStream_t stream) {
    const float* t  = (const float*)d_in[0];
    const float* y  = (const float*)d_in[1];
    const float* W1 = (const float*)d_in[2];
    const float* b1 = (const float*)d_in[3];
    const float* W2 = (const float*)d_in[4];
    const float* b2 = (const float*)d_in[5];
    const float* W3 = (const float*)d_in[6];
    const float* b3 = (const float*)d_in[7];
    float* out = (float*)d_out;

    DiagonalVariance_kernel<<<dim3(NBX, NBY), dim3(256), 0, stream>>>(
        t, y, W1, b1, W2, b2, W3, b3, out);
}

// Round 15
// 214.407 us; speedup vs baseline: 1.0136x; 1.0136x over previous
//
#include <hip/hip_runtime.h>
#include <cmath>

// Problem constants
#define B_TOTAL 262144
#define D 16
#define TE 3
#define H 64

#define TPB 16                       // b-tiles (of 16 rows) per wave
#define NBX (B_TOTAL / 16 / TPB)     // 1024 blocks in x
#define NBY 4                        // d-groups of 4 (4 waves/block, one d each)

#define LOG2E 1.44269504088896340736f
#define LN2   0.693147180559945309417f

#define RSH 72   // f16 transpose row stride (64+8 pad)
#define ARS 10   // A-frag staging stride in dwords (conflict-free b64 reads)

typedef _Float16 half8  __attribute__((ext_vector_type(8)));
typedef _Float16 half4  __attribute__((ext_vector_type(4)));
typedef __fp16   fp16x2 __attribute__((ext_vector_type(2)));
typedef float    f32x4  __attribute__((ext_vector_type(4)));
typedef unsigned int uint32;

// exp+log softplus (R12: poly regressed; serial FMA chain + VALU cost).
__device__ __forceinline__ float sp_log2(float xs) {
    return __builtin_amdgcn_logf(1.0f + __builtin_amdgcn_exp2f(xs));
}
__device__ __forceinline__ float softplus_full(float x) {
    float e = __builtin_amdgcn_exp2f(-fabsf(x) * LOG2E);
    return fmaxf(x, 0.0f) + LN2 * __builtin_amdgcn_logf(1.0f + e);
}

// R15: rotated software pipeline. R14's full 2-tile duplication spilled
// (~60 extra live regs); here only acc2 (16 regs) crosses the FRONT/EPI
// boundary: FRONT(tg) [A-read->L1 MFMA->sp->transpose->L2 MFMA] issues ahead
// of EPI(tg-1) [b2+sp+W3 dot->butterfly->obuf]; the two are independent, so
// the compiler can hide each one's latency under the other's issue stream.
__global__ __launch_bounds__(256, 4) void DiagonalVariance_kernel(
    const float* __restrict__ t,   // [B, TE]
    const float* __restrict__ y,   // [B, D]
    const float* __restrict__ W1,  // [D, 4, 64]
    const float* __restrict__ b1,  // [D, 64]
    const float* __restrict__ W2,  // [D, 64, 64]
    const float* __restrict__ b2,  // [D, 64]
    const float* __restrict__ W3,  // [D, 64, 1]
    const float* __restrict__ b3,  // [D, 1]
    float* __restrict__ out)       // [B, D]
{
    __shared__ __align__(16) _Float16 tbuf[4 * 16 * RSH];  // 9.2 KB
    __shared__ __align__(16) float obuf[TPB * 16 * 4];     // 4 KB
    __shared__ __align__(16) uint32 abuf[256 * ARS];       // 10 KB

    const int wave = threadIdx.x >> 6;
    const int lane = threadIdx.x & 63;
    const int q    = lane >> 4;
    const int lm   = lane & 15;
    const int d    = blockIdx.y * 4 + wave;
    const bool q0  = (q == 0);

    // ---- cooperative input staging: thread i pre-packs row i's A-frag ----
    {
        const int i    = threadIdx.x;
        const int grow = blockIdx.x * 256 + i;
        const f32x4 yv = *(const f32x4*)(y + grow * D + blockIdx.y * 4);
        const float* tpp = t + grow * TE;
        const float tt0 = tpp[0], tt1 = tpp[1], tt2 = tpp[2];
        const uint32 u1 = __builtin_bit_cast(uint32, __builtin_amdgcn_cvt_pkrtz(tt1, tt2));
        uint32* ab = abuf + i * ARS;
        ab[0] = __builtin_bit_cast(uint32, __builtin_amdgcn_cvt_pkrtz(yv.x, tt0)); ab[1] = u1;
        ab[2] = __builtin_bit_cast(uint32, __builtin_amdgcn_cvt_pkrtz(yv.y, tt0)); ab[3] = u1;
        ab[4] = __builtin_bit_cast(uint32, __builtin_amdgcn_cvt_pkrtz(yv.z, tt0)); ab[5] = u1;
        ab[6] = __builtin_bit_cast(uint32, __builtin_amdgcn_cvt_pkrtz(yv.w, tt0)); ab[7] = u1;
    }

    const float* __restrict__ W1d = W1 + d * (4 * H);
    const float* __restrict__ b1d = b1 + d * H;
    const float* __restrict__ W2d = W2 + d * (H * H);
    const float* __restrict__ b2d = b2 + d * H;
    const float* __restrict__ W3d = W3 + d * H;

    // ---------------- one-time per-wave fragment setup ----------------
    half8 w2f[2][4];
    #pragma unroll
    for (int ks = 0; ks < 2; ++ks)
        #pragma unroll
        for (int nt = 0; nt < 4; ++nt)
            #pragma unroll
            for (int j = 0; j < 8; ++j)
                w2f[ks][nt][j] = (_Float16)W2d[(32 * ks + 8 * q + j) * H + 16 * nt + lm];

    half4 w1f[4];
    #pragma unroll
    for (int nt = 0; nt < 4; ++nt) {
        #pragma unroll
        for (int i = 0; i < 4; ++i) {
            const int h = 16 * nt + lm;
            float v = 0.0f;
            if (q == 0)           v = W1d[i * H + h] * LOG2E;
            if (q == 1 && i == 0) v = b1d[h] * LOG2E;
            w1f[nt][i] = (_Float16)v;
        }
    }

    float b2s[4], w3n[4];
    #pragma unroll
    for (int nt = 0; nt < 4; ++nt) {
        b2s[nt] = b2d[16 * nt + lm] * LOG2E;
        w3n[nt] = W3d[16 * nt + lm] * LN2;
    }
    const float b3v = b3[d];

    _Float16* const tb  = tbuf + wave * (16 * RSH);
    _Float16* const twr = tb + (q * 4) * RSH + lm;       // + r*RSH + nt*16
    const _Float16* const trd = tb + lm * RSH + 8 * q;   // + 32*ks

    const uint32* const ard = abuf + lm * ARS + 2 * wave;

    __syncthreads();   // staging visible to all waves

    // FRONT: tile tg -> acc2 (the only cross-stage live state, 16 regs)
    auto FRONT = [&](int tg, f32x4 acc2o[4]) {
        const uint32 a0 = ard[tg * 16 * ARS + 0];
        const uint32 a1 = ard[tg * 16 * ARS + 1];
        union { half4 h; uint32 uu[2]; } af;
        af.uu[0] = q0 ? a0 : 0x00003C00u;   // q1: {1.0h,0} bias row k=4
        af.uu[1] = q0 ? a1 : 0u;            // q2/q3 garbage killed by zero B rows

        f32x4 acc1[4];
        #pragma unroll
        for (int nt = 0; nt < 4; ++nt)
            acc1[nt] = __builtin_amdgcn_mfma_f32_16x16x16f16(
                af.h, w1f[nt], (f32x4){0.f, 0.f, 0.f, 0.f}, 0, 0, 0);

        #pragma unroll
        for (int nt = 0; nt < 4; ++nt)
            #pragma unroll
            for (int r = 0; r < 4; ++r)
                twr[r * RSH + nt * 16] = (_Float16)sp_log2(acc1[nt][r]);

        half8 a2[2];
        #pragma unroll
        for (int ks = 0; ks < 2; ++ks)
            a2[ks] = *(const half8*)(trd + 32 * ks);

        #pragma unroll
        for (int nt = 0; nt < 4; ++nt)
            acc2o[nt] = __builtin_amdgcn_mfma_f32_16x16x32_f16(
                a2[0], w2f[0][nt], (f32x4){0.f, 0.f, 0.f, 0.f}, 0, 0, 0);
        #pragma unroll
        for (int nt = 0; nt < 4; ++nt)
            acc2o[nt] = __builtin_amdgcn_mfma_f32_16x16x32_f16(a2[1], w2f[1][nt], acc2o[nt], 0, 0, 0);
    };

    // EPILOGUE: acc2 of tile tg -> obuf
    auto EPI = [&](int tg, const f32x4 acc2i[4]) {
        float s[4] = {0.f, 0.f, 0.f, 0.f};
        #pragma unroll
        for (int nt = 0; nt < 4; ++nt)
            #pragma unroll
            for (int r = 0; r < 4; ++r)
                s[r] = fmaf(sp_log2(acc2i[nt][r] + b2s[nt]), w3n[nt], s[r]);

        #pragma unroll
        for (int mask = 1; mask < 16; mask <<= 1)
            #pragma unroll
            for (int r = 0; r < 4; ++r)
                s[r] += __shfl_xor(s[r], mask, 64);

        const float v01 = (lm & 1) ? s[1] : s[0];
        const float v23 = (lm & 1) ? s[3] : s[2];
        const float vs  = (lm & 2) ? v23 : v01;
        if (lm < 4)
            obuf[(tg * 16 + q * 4 + lm) * 4 + wave] = softplus_full(vs + b3v);
    };

    f32x4 accA[4], accB[4];
    FRONT(0, accA);
    #pragma unroll 1
    for (int tg = 1; tg <= TPB - 3; tg += 2) {
        FRONT(tg, accB);       // independent of EPI(tg-1): interleaves
        EPI(tg - 1, accA);
        FRONT(tg + 1, accA);
        EPI(tg, accB);
    }
    FRONT(TPB - 1, accB);
    EPI(TPB - 2, accA);
    EPI(TPB - 1, accB);

    // Single barrier, then f32x4 flush: thread i handles row i (256 rows).
    __syncthreads();
    const int i = threadIdx.x;
    const f32x4 v = *(const f32x4*)(obuf + 4 * i);
    *(f32x4*)(out + (blockIdx.x * 256 + i) * D + blockIdx.y * 4) = v;
}

extern "C" void kernel_launch(void* const* d_in, const int* in_sizes, int n_in,
                              void* d_out, int out_size, void* d_ws, size_t ws_size,
                              hipStream_t stream) {
    const float* t  = (const float*)d_in[0];
    const float* y  = (const float*)d_in[1];
    const float* W1 = (const float*)d_in[2];
    const float* b1 = (const float*)d_in[3];
    const float* W2 = (const float*)d_in[4];
    const float* b2 = (const float*)d_in[5];
    const float* W3 = (const float*)d_in[6];
    const float* b3 = (const float*)d_in[7];
    float* out = (float*)d_out;

    DiagonalVariance_kernel<<<dim3(NBX, NBY), dim3(256), 0, stream>>>(
        t, y, W1, b1, W2, b2, W3, b3, out);
}